// Round 1
// baseline (1383.894 us; speedup 1.0000x reference)
//
#include <hip/hip_runtime.h>
#include <hip/hip_bf16.h>

#define DEV static __device__ __forceinline__

typedef __attribute__((ext_vector_type(8))) short bf16x8;
typedef __attribute__((ext_vector_type(4))) float f32x4;
typedef __attribute__((ext_vector_type(4))) ushort us4;

// ---------- scalar helpers ----------
DEV ushort f2bf(float f){                 // RNE f32 -> bf16
  uint u = __builtin_bit_cast(uint, f);
  u += 0x7fffu + ((u >> 16) & 1u);
  return (ushort)(u >> 16);
}
DEV float bf2f(ushort h){
  uint u = ((uint)h) << 16;
  return __builtin_bit_cast(float, u);
}

DEV float blk_sum(float v, float* red, int tid){
  #pragma unroll
  for(int o = 32; o >= 1; o >>= 1) v += __shfl_xor(v, o, 64);
  if((tid & 63) == 0) red[tid >> 6] = v;
  __syncthreads();
  v = red[0] + red[1] + red[2] + red[3];
  __syncthreads();
  return v;
}
DEV float blk_max(float v, float* red, int tid){
  #pragma unroll
  for(int o = 32; o >= 1; o >>= 1) v = fmaxf(v, __shfl_xor(v, o, 64));
  if((tid & 63) == 0) red[tid >> 6] = v;
  __syncthreads();
  v = fmaxf(fmaxf(red[0], red[1]), fmaxf(red[2], red[3]));
  __syncthreads();
  return v;
}

// ---------- f32 -> bf16 convert (n4 = count of float4 groups) ----------
__global__ __launch_bounds__(256) void k_convert(const float* __restrict__ src,
                                                 ushort* __restrict__ dst, long n4){
  long i = (long)blockIdx.x * 256 + threadIdx.x;
  long stride = (long)gridDim.x * 256;
  for(; i < n4; i += stride){
    float4 v = ((const float4*)src)[i];
    us4 o; o.x = f2bf(v.x); o.y = f2bf(v.y); o.z = f2bf(v.z); o.w = f2bf(v.w);
    ((us4*)dst)[i] = o;
  }
}

// ---------- tile transpose (+convert to bf16, optional lo residual) ----------
// src: [R, C] (T = float or ushort-bf16), dst: [C, R] bf16. grid (C/32, R/32, z)
template<typename T, int LO>
__global__ __launch_bounds__(256) void k_transpose(const T* __restrict__ src,
    ushort* __restrict__ dst, ushort* __restrict__ dstLo,
    int R, int C, long sSrc, long sDst){
  __shared__ float tile[32][33];
  src += (long)blockIdx.z * sSrc;
  dst += (long)blockIdx.z * sDst;
  if(LO) dstLo += (long)blockIdx.z * sDst;
  int tr = blockIdx.y * 32, tc = blockIdx.x * 32;
  int tid = threadIdx.x;
  #pragma unroll
  for(int j = 0; j < 4; ++j){
    int idx = j * 256 + tid; int r = idx >> 5, c = idx & 31;
    float v;
    if constexpr (sizeof(T) == 4) v = (float)src[(long)(tr + r) * C + tc + c];
    else                          v = bf2f((ushort)src[(long)(tr + r) * C + tc + c]);
    tile[r][c] = v;
  }
  __syncthreads();
  #pragma unroll
  for(int j = 0; j < 4; ++j){
    int idx = j * 256 + tid; int r = idx >> 5, c = idx & 31;
    float v = tile[c][r];
    ushort hi = f2bf(v);
    dst[(long)(tc + r) * R + tr + c] = hi;
    if(LO) dstLo[(long)(tc + r) * R + tr + c] = f2bf(v - bf2f(hi));
  }
}

// ---------- embedding gather + pos add + LayerNorm -> bf16 ----------
__global__ __launch_bounds__(256) void k_embed_ln(const int* __restrict__ tok,
    const float* __restrict__ emb, const float* __restrict__ pos,
    const float* __restrict__ g, const float* __restrict__ be,
    ushort* __restrict__ out){
  __shared__ float red[4];
  int r = blockIdx.x, tid = threadIdx.x;
  int s = r & 2047;
  long t = tok[r];
  float4 e4 = ((const float4*)(emb + t * 1024))[tid];
  float4 p4 = ((const float4*)(pos + (long)s * 1024))[tid];
  float x0 = e4.x + p4.x, x1 = e4.y + p4.y, x2 = e4.z + p4.z, x3 = e4.w + p4.w;
  float m = blk_sum(x0 + x1 + x2 + x3, red, tid) * (1.f / 1024.f);
  float d0 = x0 - m, d1 = x1 - m, d2 = x2 - m, d3 = x3 - m;
  float v = blk_sum(d0 * d0 + d1 * d1 + d2 * d2 + d3 * d3, red, tid) * (1.f / 1024.f);
  float rs = rsqrtf(v + 1e-5f);
  float4 gv = ((const float4*)g)[tid], bv = ((const float4*)be)[tid];
  us4 o;
  o.x = f2bf(d0 * rs * gv.x + bv.x); o.y = f2bf(d1 * rs * gv.y + bv.y);
  o.z = f2bf(d2 * rs * gv.z + bv.z); o.w = f2bf(d3 * rs * gv.w + bv.w);
  ((us4*)(out + (long)r * 1024))[tid] = o;
}

// ---------- LayerNorm (f32 in, bf16 out), rows of 1024 ----------
__global__ __launch_bounds__(256) void k_ln(const float* __restrict__ X,
    const float* __restrict__ g, const float* __restrict__ be,
    ushort* __restrict__ out){
  __shared__ float red[4];
  int r = blockIdx.x, tid = threadIdx.x;
  float4 x4 = ((const float4*)(X + (long)r * 1024))[tid];
  float x0 = x4.x, x1 = x4.y, x2 = x4.z, x3 = x4.w;
  float m = blk_sum(x0 + x1 + x2 + x3, red, tid) * (1.f / 1024.f);
  float d0 = x0 - m, d1 = x1 - m, d2 = x2 - m, d3 = x3 - m;
  float v = blk_sum(d0 * d0 + d1 * d1 + d2 * d2 + d3 * d3, red, tid) * (1.f / 1024.f);
  float rs = rsqrtf(v + 1e-5f);
  float4 gv = ((const float4*)g)[tid], bv = ((const float4*)be)[tid];
  us4 o;
  o.x = f2bf(d0 * rs * gv.x + bv.x); o.y = f2bf(d1 * rs * gv.y + bv.y);
  o.z = f2bf(d2 * rs * gv.z + bv.z); o.w = f2bf(d3 * rs * gv.w + bv.w);
  ((us4*)(out + (long)r * 1024))[tid] = o;
}

// ---------- row softmax (f32 in, bf16 out; optional lo residual) ----------
// row length = CH*1024 (CH=1 or 2). one block per row.
template<int CH, int LO>
__global__ __launch_bounds__(256) void k_softmax(const float* __restrict__ S,
    ushort* __restrict__ Whi, ushort* __restrict__ Wlo, float scale){
  __shared__ float red[4];
  long r = blockIdx.x; int tid = threadIdx.x;
  const float* row = S + r * (CH * 1024);
  float x[CH * 4];
  #pragma unroll
  for(int c = 0; c < CH; ++c){
    float4 v = ((const float4*)(row + c * 1024))[tid];
    x[c*4+0] = v.x * scale; x[c*4+1] = v.y * scale;
    x[c*4+2] = v.z * scale; x[c*4+3] = v.w * scale;
  }
  float mx = x[0];
  #pragma unroll
  for(int i = 1; i < CH * 4; ++i) mx = fmaxf(mx, x[i]);
  mx = blk_max(mx, red, tid);
  float sum = 0.f;
  #pragma unroll
  for(int i = 0; i < CH * 4; ++i){ x[i] = expf(x[i] - mx); sum += x[i]; }
  sum = blk_sum(sum, red, tid);
  float inv = 1.f / sum;
  #pragma unroll
  for(int c = 0; c < CH; ++c){
    us4 o, ol;
    #pragma unroll
    for(int j = 0; j < 4; ++j){
      float wv = x[c*4+j] * inv;
      ushort hi = f2bf(wv);
      o[j] = hi;
      if(LO) ol[j] = f2bf(wv - bf2f(hi));
    }
    ((us4*)(Whi + r * (CH * 1024) + c * 1024))[tid] = o;
    if(LO) ((us4*)(Wlo + r * (CH * 1024) + c * 1024))[tid] = ol;
  }
}

// ---------- GEMM: C[M,N] = A[M,K] * B[N,K]^T (all row-major, bf16 in, f32 acc) ----------
// OUT: 0 = f32 store, 1 = bf16 store, 2 = f32 + bias
// SPLIT: 3-term hi/lo precision (A=Ahi+Alo, B=Bhi+Blo, drop lo*lo)
DEV void stage_tile(const ushort* __restrict__ g, int ld, int r0, int c0,
                    ushort* lds, int tid){
  int wave = tid >> 6;
  #pragma unroll
  for(int j = 0; j < 2; ++j){
    int e = j * 2048 + tid * 8;
    int r = e >> 5, c = e & 31;
    const ushort* gp = g + (long)(r0 + r) * ld + (c0 + c);
    ushort* lp = lds + j * 2048 + wave * 512;   // wave-uniform base; HW adds lane*16B
    __builtin_amdgcn_global_load_lds((const __attribute__((address_space(1))) void*)gp,
                                     (__attribute__((address_space(3))) void*)lp,
                                     16, 0, 0);
  }
}

template<int OUT, int SPLIT>
__global__ __launch_bounds__(256) void k_gemm(
    const ushort* __restrict__ A, const ushort* __restrict__ Alo,
    const ushort* __restrict__ B, const ushort* __restrict__ Blo,
    void* __restrict__ Cout, const float* __restrict__ bias,
    int N, int K, long sA, long sB, long sC){
  constexpr int NB = SPLIT ? 2 : 1;
  __shared__ ushort As[2][NB][4096];
  __shared__ ushort Bs[2][NB][4096];
  long z = (long)blockIdx.z;
  A += z * sA; B += z * sB;
  if(SPLIT){ Alo += z * sA; Blo += z * sB; }
  int brow = blockIdx.y * 128, bcol = blockIdx.x * 128;
  int tid = threadIdx.x, lane = tid & 63, wave = tid >> 6;
  int wr = wave >> 1, wc = wave & 1, lr = lane & 15, lq = lane >> 4;
  f32x4 acc[4][4] = {};
  int nt = K >> 5;

  auto stage = [&](int buf, int t){
    stage_tile(A, K, brow, t * 32, &As[buf][0][0], tid);
    stage_tile(B, K, bcol, t * 32, &Bs[buf][0][0], tid);
    if constexpr(SPLIT){
      stage_tile(Alo, K, brow, t * 32, &As[buf][1][0], tid);
      stage_tile(Blo, K, bcol, t * 32, &Bs[buf][1][0], tid);
    }
  };
  stage(0, 0);
  __syncthreads();
  int cur = 0;
  for(int t = 0; t < nt; ++t){
    if(t + 1 < nt) stage(cur ^ 1, t + 1);
    const int ka = lq * 8;
    bf16x8 a[4], b[4], al[4], bl[4];
    #pragma unroll
    for(int m = 0; m < 4; ++m){
      a[m] = *(const bf16x8*)(&As[cur][0][(wr*64 + m*16 + lr)*32 + ka]);
      if constexpr(SPLIT) al[m] = *(const bf16x8*)(&As[cur][1][(wr*64 + m*16 + lr)*32 + ka]);
    }
    #pragma unroll
    for(int n = 0; n < 4; ++n){
      b[n] = *(const bf16x8*)(&Bs[cur][0][(wc*64 + n*16 + lr)*32 + ka]);
      if constexpr(SPLIT) bl[n] = *(const bf16x8*)(&Bs[cur][1][(wc*64 + n*16 + lr)*32 + ka]);
    }
    #pragma unroll
    for(int m = 0; m < 4; ++m)
      #pragma unroll
      for(int n = 0; n < 4; ++n){
        acc[m][n] = __builtin_amdgcn_mfma_f32_16x16x32_bf16(a[m], b[n], acc[m][n], 0, 0, 0);
        if constexpr(SPLIT){
          acc[m][n] = __builtin_amdgcn_mfma_f32_16x16x32_bf16(a[m], bl[n], acc[m][n], 0, 0, 0);
          acc[m][n] = __builtin_amdgcn_mfma_f32_16x16x32_bf16(al[m], b[n], acc[m][n], 0, 0, 0);
        }
      }
    __syncthreads();
    cur ^= 1;
  }
  long row0 = brow + wr * 64 + lq * 4;
  long col0 = bcol + wc * 64 + lr;
  if constexpr(OUT == 1){
    ushort* C = (ushort*)Cout + z * sC;
    #pragma unroll
    for(int m = 0; m < 4; ++m)
      #pragma unroll
      for(int n = 0; n < 4; ++n){
        #pragma unroll
        for(int q = 0; q < 4; ++q)
          C[(row0 + m*16 + q) * (long)N + col0 + n*16] = f2bf(acc[m][n][q]);
      }
  } else {
    float* C = (float*)Cout + z * sC;
    #pragma unroll
    for(int n = 0; n < 4; ++n){
      float bb = 0.f;
      if constexpr(OUT == 2) bb = bias[col0 + n*16];
      #pragma unroll
      for(int m = 0; m < 4; ++m){
        #pragma unroll
        for(int q = 0; q < 4; ++q)
          C[(row0 + m*16 + q) * (long)N + col0 + n*16] = acc[m][n][q] + bb;
      }
    }
  }
}

// ---------- host ----------
extern "C" void kernel_launch(void* const* d_in, const int* in_sizes, int n_in,
                              void* d_out, int out_size, void* d_ws, size_t ws_size,
                              hipStream_t stream){
  const int*   tok     = (const int*)d_in[0];
  const float* tok_emb = (const float*)d_in[1];
  const float* pos_emb = (const float*)d_in[2];
  const float* p_key   = (const float*)d_in[3];
  const float* p_value = (const float*)d_in[4];
  const float* fc_w    = (const float*)d_in[5];
  const float* fc_b    = (const float*)d_in[6];
  const float* ln1_g = (const float*)d_in[7],  *ln1_b = (const float*)d_in[8];
  const float* ln2_g = (const float*)d_in[9],  *ln2_b = (const float*)d_in[10];
  const float* ln3_g = (const float*)d_in[11], *ln3_b = (const float*)d_in[12];
  const float* ln4_g = (const float*)d_in[13], *ln4_b = (const float*)d_in[14];
  float* out = (float*)d_out;

  const long VD = 32000L * 1024;
  char* base = (char*)d_ws; size_t off = 0;
  auto alloc = [&](size_t sz){ void* p = base + off; off += (sz + 255) & ~(size_t)255; return p; };
  ushort* fcw   = (ushort*)alloc(VD * 2);             // fc_w bf16 [V, D]
  ushort* pk    = (ushort*)alloc(1024L * 1024 * 2);   // p_key bf16 [P, D]
  ushort* pvT   = (ushort*)alloc(1024L * 1024 * 2);   // p_value^T hi [D, P]
  ushort* pvTlo = (ushort*)alloc(1024L * 1024 * 2);   // p_value^T lo
  ushort* Xn    = (ushort*)alloc(4096L * 1024 * 2);   // current LN output (bf16)
  float*  Sb    = (float*)alloc(2L * 2048 * 2048 * 4);// scores (pattention or attn)
  ushort* Whi   = (ushort*)alloc(2L * 2048 * 2048 * 2);// softmax weights hi
  ushort* Wlo   = (ushort*)alloc(4096L * 1024 * 2);   // softmax weights lo (pattention)
  ushort* Qb    = (ushort*)alloc(4096L * 1024 * 2);   // Q bf16 [B,S,D]
  ushort* QT    = (ushort*)alloc(4096L * 1024 * 2);   // Q^T bf16 [B,D,S]
  float*  PV    = (float*)alloc(4096L * 1024 * 4);    // f32 activation (Xatt/Oatt/Xffn)

  const float inv_scale = 0.03125f;  // 1/sqrt(1024)

  // weight preprocessing (ws is re-poisoned every call, so redo each call)
  k_convert<<<4096, 256, 0, stream>>>(fc_w, fcw, VD / 4);
  k_convert<<<512, 256, 0, stream>>>(p_key, pk, 1024L * 1024 / 4);
  k_transpose<float, 1><<<dim3(32, 32, 1), 256, 0, stream>>>(p_value, pvT, pvTlo, 1024, 1024, 0, 0);

  // embed + pos + LN1
  k_embed_ln<<<4096, 256, 0, stream>>>(tok, tok_emb, pos_emb, ln1_g, ln1_b, Xn);

  // pattention: X -> scores -> softmax(hi/lo) -> PV(split) ; out bf16 (Q) or f32
  auto patt = [&](ushort* Xin, int bf16_out, void* Out){
    k_gemm<0,0><<<dim3(8, 32, 1), 256, 0, stream>>>(Xin, nullptr, pk, nullptr, Sb, nullptr, 1024, 1024, 0, 0, 0);
    k_softmax<1,1><<<4096, 256, 0, stream>>>(Sb, Whi, Wlo, inv_scale);
    if(bf16_out) k_gemm<1,1><<<dim3(8, 32, 1), 256, 0, stream>>>(Whi, Wlo, pvT, pvTlo, Out, nullptr, 1024, 1024, 0, 0, 0);
    else         k_gemm<0,1><<<dim3(8, 32, 1), 256, 0, stream>>>(Whi, Wlo, pvT, pvTlo, Out, nullptr, 1024, 1024, 0, 0, 0);
  };

  patt(Xn, 1, Qb);   // Q = pattention(LN1(X))

  // self-attention: S2 = Q Q^T / 32 ; softmax ; Xatt = attn @ Q
  k_gemm<0,0><<<dim3(16, 16, 2), 256, 0, stream>>>(Qb, nullptr, Qb, nullptr, Sb, nullptr,
      2048, 1024, 2048L * 1024, 2048L * 1024, 2048L * 2048);
  k_softmax<2,0><<<4096, 256, 0, stream>>>(Sb, Whi, nullptr, inv_scale);
  k_transpose<ushort, 0><<<dim3(32, 64, 2), 256, 0, stream>>>(Qb, QT, nullptr, 2048, 1024,
      2048L * 1024, 2048L * 1024);
  k_gemm<0,0><<<dim3(8, 16, 2), 256, 0, stream>>>(Whi, nullptr, QT, nullptr, PV, nullptr,
      1024, 2048, 2048L * 2048, 2048L * 1024, 2048L * 1024);

  k_ln<<<4096, 256, 0, stream>>>(PV, ln2_g, ln2_b, Xn);   // Xatt_norm
  patt(Xn, 0, PV);                                         // Oatt
  k_ln<<<4096, 256, 0, stream>>>(PV, ln3_g, ln3_b, Xn);   // Oatt_norm
  patt(Xn, 0, PV);                                         // Xffn
  k_ln<<<4096, 256, 0, stream>>>(PV, ln4_g, ln4_b, Xn);   // Xffn_norm

  // logits = Xn @ fc_w^T + fc_b
  k_gemm<2,0><<<dim3(250, 32, 1), 256, 0, stream>>>(Xn, nullptr, fcw, nullptr, out, fc_b,
      32000, 1024, 0, 0, 0);
}